// Round 7
// baseline (278.930 us; speedup 1.0000x reference)
//
#include <hip/hip_runtime.h>
#include <stdint.h>

// SpikeMLP via exact fixed-point i8 MFMA.
// w -> n = rint(w * 2^42), 5 signed base-256 digits; spikes are {0,1} i8.
// Per-limb i32 MFMA sums exact; i64 Horner exact; f64 scale exact (absmax
// 0.0 in rounds 4/5/6 with identical numerics).
// This round: A lives in HBM in MFMA-fragment-linear order (AF) -> coalesced
// dwordx4 register fragments, no A LDS. B staged via global_load_lds(16)
// directly into fragment-linear LDS (linear dst, no write conflicts, no
// staging regs). BK=64 (1 barrier / 2 K-tiles). 4-wave blocks, 2 blocks/CU.
// A and B use the SAME (row,k)->(lane,byte) map, so any internal MFMA k-slot
// permutation cancels; C/D layout decoded at runtime with uniform-byte MFMAs.

typedef int v4i __attribute__((ext_vector_type(4)));
typedef int v16i __attribute__((ext_vector_type(16)));

#define TT 16
constexpr int KD = 2048;
constexpr double SCALE = 4398046511104.0;   // 2^42

#define GLOAD_LDS16(g, s)                                                      \
  __builtin_amdgcn_global_load_lds(                                            \
      (const __attribute__((address_space(1))) uint32_t*)(g),                  \
      (__attribute__((address_space(3))) uint32_t*)(s), 16, 0, 0)

// AF fragment-linear layout: [mtile][ktile(64)][lane][16B],
// lane = (m&31) + 32*((k>>4)&1), byte = k&15.
__device__ __forceinline__ size_t af_addr(int m, int k) {
  return ((size_t)((m >> 5) * 64 + (k >> 5)) << 10)
       + ((size_t)((m & 31) + (((k >> 4) & 1) << 5)) << 4) + (k & 15);
}

// ---------- weight -> 5 signed-digit i8 planes ----------
__global__ __launch_bounds__(256)
void prep_limbs(const float* __restrict__ W, int8_t* __restrict__ dst, int total) {
  const int i4 = (blockIdx.x * 256 + threadIdx.x) * 4;
  if (i4 >= total) return;
  const float4 wv = *reinterpret_cast<const float4*>(W + i4);
  long long n[4];
  n[0] = (long long)rint((double)wv.x * SCALE);
  n[1] = (long long)rint((double)wv.y * SCALE);
  n[2] = (long long)rint((double)wv.z * SCALE);
  n[3] = (long long)rint((double)wv.w * SCALE);
#pragma unroll
  for (int l = 0; l < 5; ++l) {
    char c[4];
#pragma unroll
    for (int e = 0; e < 4; ++e) {
      const int d = (int)((n[e] + 128) & 255) - 128;   // balanced digit
      c[e] = (char)d;
      n[e] = (n[e] - d) >> 8;
    }
    *reinterpret_cast<char4*>(dst + (size_t)l * total + i4) =
        make_char4(c[0], c[1], c[2], c[3]);
  }
}

// ---------- [B][IN][T] f32 -> AF fragment-linear i8 spikes ----------
__global__ __launch_bounds__(256)
void transpose_x_af(const float* __restrict__ in, int8_t* __restrict__ out) {
  const int idx = blockIdx.x * 256 + threadIdx.x;       // (b, i), i fastest
  const float4* src = reinterpret_cast<const float4*>(in) + (size_t)idx * 4;
  float4 v[4];
  v[0] = src[0]; v[1] = src[1]; v[2] = src[2]; v[3] = src[3];
  const float* f = reinterpret_cast<const float*>(v);
  const int b = idx >> 11, i = idx & 2047;
  const size_t base = af_addr(b * TT, i);   // (b*16+t): lane advances by t
#pragma unroll
  for (int t = 0; t < TT; ++t) out[base + (size_t)t * 16] = (int8_t)f[t];
}

static __device__ __forceinline__ v16i zero16() {
  v16i z;
#pragma unroll
  for (int i = 0; i < 16; ++i) z[i] = 0;
  return z;
}

// ---------- fused i8 GEMM (5 limbs) + CLIF scan ----------
// 256 thr / 4 waves; BM=128, BN=64, BK=64. Wave (wy=w>>1, nsub=w&1) owns a
// 64x32 output tile. A frags from AF (global, coalesced, reg-prefetched);
// B via global_load_lds into fragment-linear dbuf LDS.
template<int N, bool FINAL>
__global__ __launch_bounds__(256, 2)
void gemm_scan_i8(const int8_t* __restrict__ AF,   // fragment-linear spikes
                  const int8_t* __restrict__ WL,   // [5][N][2048] limbs
                  const float* __restrict__ bias,  // [N]
                  void* __restrict__ outp) {
  __shared__ union SM {
    int8_t b[2][20 * 1024];      // dbuf B: frag f=l*4+kk*2+ns at f*1024
    double c[4][32 * 33];        // per-wave epilogue C tile (33.8 KB)
  } sm;

  const int tid = threadIdx.x;
  const int lane = tid & 63;
  const int w = tid >> 6;
  const int wy = w >> 1, nsub = w & 1;
  const int m0 = blockIdx.x * 128;
  const int n0 = blockIdx.y * 64;
  const size_t lst = (size_t)N * KD;

  // B DMA jobs: 5 per wave; job j -> frag f = w + 4j; l=f>>2, kk=(f>>1)&1, ns=f&1
  const int8_t* bsrc[5];
  int bdst[5];
#pragma unroll
  for (int j = 0; j < 5; ++j) {
    const int f = w + 4 * j;
    const int l = f >> 2, kk = (f >> 1) & 1, ns = f & 1;
    bsrc[j] = WL + (size_t)l * lst + (size_t)(n0 + ns * 32 + (lane & 31)) * KD
            + kk * 32 + ((lane >> 5) << 4);
    bdst[j] = f * 1024;
  }

  // A fragment pointers: base per mi; ktile offset = (2*t2+kk)*1024
  const int8_t* aP[2];
#pragma unroll
  for (int mi = 0; mi < 2; ++mi)
    aP[mi] = AF + ((size_t)((m0 >> 5) + wy * 2 + mi) << 16) + lane * 16;

  v16i acc[5][2];
#pragma unroll
  for (int l = 0; l < 5; ++l) { acc[l][0] = zero16(); acc[l][1] = zero16(); }

  // prologue: B(0) -> buf0 via DMA; A(0) -> regs
#pragma unroll
  for (int j = 0; j < 5; ++j) GLOAD_LDS16(bsrc[j], &sm.b[0][bdst[j]]);
  v4i aC[2][2];
#pragma unroll
  for (int mi = 0; mi < 2; ++mi)
#pragma unroll
    for (int kk = 0; kk < 2; ++kk)
      aC[mi][kk] = *(const v4i*)(aP[mi] + kk * 1024);
  __syncthreads();   // drains vmcnt: buf0 ready

  constexpr int NT2 = KD / 64;   // 32 super-tiles
  for (int t2 = 0; t2 < NT2; ++t2) {
    const int cur = t2 & 1;
    v4i aN[2][2];
    if (t2 + 1 < NT2) {          // issue next tile's loads first (latency)
#pragma unroll
      for (int j = 0; j < 5; ++j)
        GLOAD_LDS16(bsrc[j] + (t2 + 1) * 64, &sm.b[cur ^ 1][bdst[j]]);
#pragma unroll
      for (int mi = 0; mi < 2; ++mi)
#pragma unroll
        for (int kk = 0; kk < 2; ++kk)
          aN[mi][kk] = *(const v4i*)(aP[mi] + ((t2 + 1) * 2 + kk) * 1024);
    }
    const int8_t* bb = sm.b[cur];
    __builtin_amdgcn_s_setprio(1);
#pragma unroll
    for (int l = 0; l < 5; ++l)
#pragma unroll
      for (int kk = 0; kk < 2; ++kk) {
        const v4i bf = *(const v4i*)(bb + ((l * 4 + kk * 2 + nsub) << 10) + lane * 16);
        acc[l][0] = __builtin_amdgcn_mfma_i32_32x32x32_i8(aC[0][kk], bf, acc[l][0], 0, 0, 0);
        acc[l][1] = __builtin_amdgcn_mfma_i32_32x32x32_i8(aC[1][kk], bf, acc[l][1], 0, 0, 0);
      }
    __builtin_amdgcn_s_setprio(0);
    __syncthreads();             // vmcnt drained: next buf + aN ready
    if (t2 + 1 < NT2) {
#pragma unroll
      for (int mi = 0; mi < 2; ++mi)
#pragma unroll
        for (int kk = 0; kk < 2; ++kk) aC[mi][kk] = aN[mi][kk];
    }
  }

  // ---- decode D layout at runtime (uniform-byte MFMAs, permutation-immune)
  const int rep = (lane & 31) * 0x01010101;
  v4i rowv; rowv[0] = rep; rowv[1] = rep; rowv[2] = rep; rowv[3] = rep;
  v4i onev; onev[0] = 0x01010101; onev[1] = 0x01010101;
            onev[2] = 0x01010101; onev[3] = 0x01010101;
  const v16i drow = __builtin_amdgcn_mfma_i32_32x32x32_i8(rowv, onev, zero16(), 0, 0, 0);
  const v16i dcol = __builtin_amdgcn_mfma_i32_32x32x32_i8(onev, rowv, zero16(), 0, 0, 0);

  // ---- epilogue: 2 passes (mi); combine limbs, scatter f64, CLIF scan ----
  const int col = lane & 31;
  const int bl = lane >> 5;
  double* cw = sm.c[w];
#pragma unroll
  for (int mi = 0; mi < 2; ++mi) {
    __syncthreads();             // staging dead / previous pass done
#pragma unroll
    for (int i = 0; i < 16; ++i) {
      long long ts = acc[4][mi][i];
      ts = (ts << 8) + acc[3][mi][i];
      ts = (ts << 8) + acc[2][mi][i];
      ts = (ts << 8) + acc[1][mi][i];
      ts = (ts << 8) + acc[0][mi][i];
      cw[(drow[i] >> 5) * 33 + (dcol[i] >> 5)] = (double)ts * 0x1p-42;
    }
    __syncthreads();

    const int gn = n0 + nsub * 32 + col;              // global column
    const int gm = m0 + (wy * 2 + mi) * 32 + bl * 16; // global row of t=0
    const double bj = (double)bias[gn];
    double cc = 0.0, vv = 0.0, ss = 0.0;
    if (!FINAL) {
      int8_t* so = (int8_t*)outp;                     // next layer's AF
      const size_t ab = af_addr(gm, gn);              // +t*16 per step
#pragma unroll
      for (int t = 0; t < TT; ++t) {
        const double x = cw[(bl * 16 + t) * 33 + col] + bj;
        cc = cc * 0.5 + x;                    // NEURON_CDECAY
        vv = vv * 0.75 * (1.0 - ss) + cc;     // NEURON_VDECAY, soft reset
        ss = (vv > 0.5) ? 1.0 : 0.0;          // NEURON_VTH
        so[ab + (size_t)t * 16] = (int8_t)ss;
      }
    } else {
      float tot = 0.0f;
#pragma unroll
      for (int t = 0; t < TT; ++t) {
        const double x = cw[(bl * 16 + t) * 33 + col] + bj;
        cc = cc * 0.5 + x;
        vv = vv * 0.75 * (1.0 - ss) + cc;
        ss = (vv > 0.5) ? 1.0 : 0.0;
        tot += (float)ss;
      }
      ((float*)outp)[(size_t)(gm / TT) * N + gn] = tot * 0.0625f;
    }
  }
}

extern "C" void kernel_launch(void* const* d_in, const int* in_sizes, int n_in,
                              void* d_out, int out_size, void* d_ws, size_t ws_size,
                              hipStream_t stream) {
  const float* X  = (const float*)d_in[0];  // [256][2048][16]
  const float* W0 = (const float*)d_in[1];  // [2048][2048]
  const float* b0 = (const float*)d_in[2];
  const float* W1 = (const float*)d_in[3];  // [2048][2048]
  const float* b1 = (const float*)d_in[4];
  const float* Wo = (const float*)d_in[5];  // [1024][2048]
  const float* bo = (const float*)d_in[6];
  float* out = (float*)d_out;               // [256][1024]

  int8_t* base = (int8_t*)d_ws;
  int8_t* AF0 = base;                                   // 8.39 MB
  int8_t* AF1 = base + (size_t)8388608;                 // 8.39 MB
  int8_t* AF2 = AF0;                                    // reuse after layer 0
  int8_t* L0  = base + (size_t)16777216;                // 21 MB
  int8_t* L1  = base + (size_t)37748736;                // 21 MB
  int8_t* Lo  = base + (size_t)58720256;                // 10.5 MB

  prep_limbs<<<(2048 * 2048 / 4 + 255) / 256, 256, 0, stream>>>(W0, L0, 2048 * 2048);
  prep_limbs<<<(2048 * 2048 / 4 + 255) / 256, 256, 0, stream>>>(W1, L1, 2048 * 2048);
  prep_limbs<<<(1024 * 2048 / 4 + 255) / 256, 256, 0, stream>>>(Wo, Lo, 1024 * 2048);
  transpose_x_af<<<2048, 256, 0, stream>>>(X, AF0);

  gemm_scan_i8<2048, false><<<dim3(32, 32), 256, 0, stream>>>(AF0, L0, b0, AF1);
  gemm_scan_i8<2048, false><<<dim3(32, 32), 256, 0, stream>>>(AF1, L1, b1, AF2);
  gemm_scan_i8<1024, true ><<<dim3(32, 16), 256, 0, stream>>>(AF2, Lo, bo, out);
}